// Round 1
// baseline (27.042 us; speedup 1.0000x reference)
//
#include <hip/hip_runtime.h>

#define B 4
#define N 512
#define HID 64
#define HEADS 4
#define DH 16
#define SCALE 0.25f
#define NEG (-1e9f)
#define LN_EPS 1e-5f

constexpr int ROWS = B * N;                       // 2048
constexpr size_t OFF_ST  = 0;
constexpr size_t OFF_Q   = (size_t)ROWS * HID;    // 131072 floats
constexpr size_t OFF_K   = 2 * OFF_Q;
constexpr size_t OFF_V   = 3 * OFF_Q;
constexpr size_t OFF_MSG = 4 * OFF_Q;             // total ws use: 5*131072 f32 = 2.62 MB

// ---------------------------------------------------------------------------
// Kernel A: fused projections. ST = x@W1+b1, Q = x@W3+b3, K = x@W4+b4, V = x@W2+b2
// grid 128 blocks x 256 thr; block handles 16 rows; wave m handles one W matrix.
// ---------------------------------------------------------------------------
__global__ __launch_bounds__(256) void proj_kernel(
    const float* __restrict__ x,
    const float* __restrict__ W1w, const float* __restrict__ W1b,
    const float* __restrict__ W2w, const float* __restrict__ W2b,
    const float* __restrict__ W3w, const float* __restrict__ W3b,
    const float* __restrict__ W4w, const float* __restrict__ W4b,
    float* __restrict__ ws)
{
  __shared__ float xsT[64 * 20];     // [k][r], row stride 20 floats (16B-aligned, depadded banks)
  const int t = threadIdx.x;
  const int rows0 = blockIdx.x * 16;

  // stage x[rows0..rows0+15][0..63] transposed: thread t loads one float4
  {
    const float4 v = *(const float4*)&x[(size_t)rows0 * HID + t * 4];
    const int r = t >> 4;            // row 0..15
    const int k0 = (t & 15) * 4;     // col 0..60
    xsT[(k0 + 0) * 20 + r] = v.x;
    xsT[(k0 + 1) * 20 + r] = v.y;
    xsT[(k0 + 2) * 20 + r] = v.z;
    xsT[(k0 + 3) * 20 + r] = v.w;
  }
  __syncthreads();

  const int m = t >> 6;              // which matrix (one per wave)
  const int c = t & 63;              // output column
  const float* Ww; const float* Wb; size_t off;
  if      (m == 0) { Ww = W1w; Wb = W1b; off = OFF_ST; }
  else if (m == 1) { Ww = W3w; Wb = W3b; off = OFF_Q;  }
  else if (m == 2) { Ww = W4w; Wb = W4b; off = OFF_K;  }
  else             { Ww = W2w; Wb = W2b; off = OFF_V;  }

  float acc[16];
#pragma unroll
  for (int r = 0; r < 16; ++r) acc[r] = 0.f;

#pragma unroll 8
  for (int k = 0; k < 64; ++k) {
    const float w = Ww[(k << 6) + c];              // coalesced per wave
    const float* xr = &xsT[k * 20];                // wave-uniform -> LDS broadcast
    const float4 a0 = *(const float4*)(xr);
    const float4 a1 = *(const float4*)(xr + 4);
    const float4 a2 = *(const float4*)(xr + 8);
    const float4 a3 = *(const float4*)(xr + 12);
    acc[0]  = fmaf(a0.x, w, acc[0]);  acc[1]  = fmaf(a0.y, w, acc[1]);
    acc[2]  = fmaf(a0.z, w, acc[2]);  acc[3]  = fmaf(a0.w, w, acc[3]);
    acc[4]  = fmaf(a1.x, w, acc[4]);  acc[5]  = fmaf(a1.y, w, acc[5]);
    acc[6]  = fmaf(a1.z, w, acc[6]);  acc[7]  = fmaf(a1.w, w, acc[7]);
    acc[8]  = fmaf(a2.x, w, acc[8]);  acc[9]  = fmaf(a2.y, w, acc[9]);
    acc[10] = fmaf(a2.z, w, acc[10]); acc[11] = fmaf(a2.w, w, acc[11]);
    acc[12] = fmaf(a3.x, w, acc[12]); acc[13] = fmaf(a3.y, w, acc[13]);
    acc[14] = fmaf(a3.z, w, acc[14]); acc[15] = fmaf(a3.w, w, acc[15]);
  }

  const float bias = Wb[c];
  const size_t base = off + (size_t)rows0 * HID + c;
#pragma unroll
  for (int r = 0; r < 16; ++r)
    ws[base + (size_t)r * HID] = acc[r] + bias;
}

// ---------------------------------------------------------------------------
// Kernel B: fused masked-edge attention per (b, h, 16-row i-tile).
// grid (32, 4, 4) x 256 thr. K/V for (b,h) staged in LDS (row stride 20 f32).
// Thread (il, g): row i = i0+il, j = g + 16*jj. Online softmax w/ rare rescale.
// ---------------------------------------------------------------------------
__global__ __launch_bounds__(256, 2) void attn_kernel(
    const int*   __restrict__ adj,
    const float* __restrict__ efeat,
    const float* __restrict__ W5w, const float* __restrict__ W5b,
    float* __restrict__ ws)
{
  __shared__ float Ksh[N * 20];     // 40 KB
  __shared__ float Vsh[N * 20];     // 40 KB

  const int it = blockIdx.x, h = blockIdx.y, b = blockIdx.z;
  const int t = threadIdx.x;
  const int g  = t & 15;            // j-subset
  const int il = t >> 4;            // local row 0..15
  const int i  = it * 16 + il;

  const float* Qb = ws + OFF_Q;
  const float* Kb = ws + OFF_K;
  const float* Vb = ws + OFF_V;
  float* msg = ws + OFF_MSG;

  // stage K,V (head slice) into LDS
  {
    const int jj = t >> 2;
    const int dq = (t & 3) << 2;
#pragma unroll
    for (int p = 0; p < 8; ++p) {
      const int j = jj + (p << 6);
      const size_t gb = ((size_t)(b * N + j)) * HID + h * DH + dq;
      *(float4*)&Ksh[j * 20 + dq] = *(const float4*)&Kb[gb];
      *(float4*)&Vsh[j * 20 + dq] = *(const float4*)&Vb[gb];
    }
  }

  // Q fragment + edge scalars (qw5 = Q.w5_h, qb5 = Q.b5_h)
  const float* qrow = Qb + ((size_t)(b * N + i)) * HID + h * DH;
  const float4 q0 = *(const float4*)(qrow);
  const float4 q1 = *(const float4*)(qrow + 4);
  const float4 q2 = *(const float4*)(qrow + 8);
  const float4 q3 = *(const float4*)(qrow + 12);
  const float4 w50 = *(const float4*)&W5w[h * DH];
  const float4 w51 = *(const float4*)&W5w[h * DH + 4];
  const float4 w52 = *(const float4*)&W5w[h * DH + 8];
  const float4 w53 = *(const float4*)&W5w[h * DH + 12];
  const float4 b50 = *(const float4*)&W5b[h * DH];
  const float4 b51 = *(const float4*)&W5b[h * DH + 4];
  const float4 b52 = *(const float4*)&W5b[h * DH + 8];
  const float4 b53 = *(const float4*)&W5b[h * DH + 12];
  float qw5 = q0.x*w50.x + q0.y*w50.y + q0.z*w50.z + q0.w*w50.w
            + q1.x*w51.x + q1.y*w51.y + q1.z*w51.z + q1.w*w51.w
            + q2.x*w52.x + q2.y*w52.y + q2.z*w52.z + q2.w*w52.w
            + q3.x*w53.x + q3.y*w53.y + q3.z*w53.z + q3.w*w53.w;
  float qb5 = q0.x*b50.x + q0.y*b50.y + q0.z*b50.z + q0.w*b50.w
            + q1.x*b51.x + q1.y*b51.y + q1.z*b51.z + q1.w*b51.w
            + q2.x*b52.x + q2.y*b52.y + q2.z*b52.z + q2.w*b52.w
            + q3.x*b53.x + q3.y*b53.y + q3.z*b53.z + q3.w*b53.w;

  __syncthreads();

  const int*   adjRow = adj   + ((size_t)(b * N + i)) * N;
  const float* eRow   = efeat + ((size_t)(b * N + i)) * N;

  float m = -3.0e38f, l = 0.f;
  float acc[16];
#pragma unroll
  for (int d = 0; d < 16; ++d) acc[d] = 0.f;

  for (int jj = 0; jj < 32; ++jj) {
    const int j = g + (jj << 4);
    const int   a  = adjRow[j];      // 16 lanes -> 64B coalesced
    const float ev = eRow[j];
    const float* kr = &Ksh[j * 20];
    const float4 k0 = *(const float4*)(kr);
    const float4 k1 = *(const float4*)(kr + 4);
    const float4 k2 = *(const float4*)(kr + 8);
    const float4 k3 = *(const float4*)(kr + 12);
    float sA = q0.x*k0.x, sB = q0.y*k0.y, sC = q0.z*k0.z, sD = q0.w*k0.w;
    sA = fmaf(q1.x, k1.x, sA); sB = fmaf(q1.y, k1.y, sB);
    sC = fmaf(q1.z, k1.z, sC); sD = fmaf(q1.w, k1.w, sD);
    sA = fmaf(q2.x, k2.x, sA); sB = fmaf(q2.y, k2.y, sB);
    sC = fmaf(q2.z, k2.z, sC); sD = fmaf(q2.w, k2.w, sD);
    sA = fmaf(q3.x, k3.x, sA); sB = fmaf(q3.y, k3.y, sB);
    sC = fmaf(q3.z, k3.z, sC); sD = fmaf(q3.w, k3.w, sD);
    float s = ((sA + sB) + (sC + sD) + ev * qw5 + qb5) * SCALE;
    s = (a == 0) ? NEG : s;          // mask after scaling, NEG unscaled (matches ref)

    float p;
    if (s > m) {                     // rare record-high: rescale state
      const float sc = __expf(m - s);
      l *= sc;
#pragma unroll
      for (int d = 0; d < 16; ++d) acc[d] *= sc;
      m = s;
      p = 1.f;
    } else {
      p = __expf(s - m);
    }
    l += p;

    const float* vr = &Vsh[j * 20];
    const float4 v0 = *(const float4*)(vr);
    const float4 v1 = *(const float4*)(vr + 4);
    const float4 v2 = *(const float4*)(vr + 8);
    const float4 v3 = *(const float4*)(vr + 12);
    acc[0]  = fmaf(p, v0.x, acc[0]);  acc[1]  = fmaf(p, v0.y, acc[1]);
    acc[2]  = fmaf(p, v0.z, acc[2]);  acc[3]  = fmaf(p, v0.w, acc[3]);
    acc[4]  = fmaf(p, v1.x, acc[4]);  acc[5]  = fmaf(p, v1.y, acc[5]);
    acc[6]  = fmaf(p, v1.z, acc[6]);  acc[7]  = fmaf(p, v1.w, acc[7]);
    acc[8]  = fmaf(p, v2.x, acc[8]);  acc[9]  = fmaf(p, v2.y, acc[9]);
    acc[10] = fmaf(p, v2.z, acc[10]); acc[11] = fmaf(p, v2.w, acc[11]);
    acc[12] = fmaf(p, v3.x, acc[12]); acc[13] = fmaf(p, v3.y, acc[13]);
    acc[14] = fmaf(p, v3.z, acc[14]); acc[15] = fmaf(p, v3.w, acc[15]);
  }

  // combine the 16 j-threads of each row: max + denom via shfl (contiguous 16-lane groups)
  float M = m;
#pragma unroll
  for (int o = 1; o < 16; o <<= 1) M = fmaxf(M, __shfl_xor(M, o, 16));
  const float wgt = __expf(m - M);
  float lw = l * wgt;
#pragma unroll
  for (int o = 1; o < 16; o <<= 1) lw += __shfl_xor(lw, o, 16);

  // weighted-accumulator transpose-reduce through LDS (reuse Ksh)
  __syncthreads();                   // all score-loop LDS reads done
  float* P = Ksh;                    // [256 threads][stride 20]
  const int prow = (il * 16 + g) * 20;
  *(float4*)&P[prow +  0] = make_float4(acc[0]*wgt,  acc[1]*wgt,  acc[2]*wgt,  acc[3]*wgt);
  *(float4*)&P[prow +  4] = make_float4(acc[4]*wgt,  acc[5]*wgt,  acc[6]*wgt,  acc[7]*wgt);
  *(float4*)&P[prow +  8] = make_float4(acc[8]*wgt,  acc[9]*wgt,  acc[10]*wgt, acc[11]*wgt);
  *(float4*)&P[prow + 12] = make_float4(acc[12]*wgt, acc[13]*wgt, acc[14]*wgt, acc[15]*wgt);
  __syncthreads();

  float ssum = 0.f;
#pragma unroll
  for (int gp = 0; gp < 16; ++gp)
    ssum += P[(il * 16 + gp) * 20 + g];    // lanes read consecutive d -> conflict-free

  msg[((size_t)(b * N + i)) * HID + h * DH + g] = ssum * (1.0f / lw);
}

// ---------------------------------------------------------------------------
// Kernel C: out = LayerNorm(x + self_t + msg). One wave per row.
// ---------------------------------------------------------------------------
__global__ __launch_bounds__(256) void ln_kernel(
    const float* __restrict__ x, const float* __restrict__ ws,
    const float* __restrict__ gamma, const float* __restrict__ beta,
    float* __restrict__ out)
{
  const int t = threadIdx.x;
  const int lane = t & 63;
  const int row = blockIdx.x * 4 + (t >> 6);
  const size_t idx = (size_t)row * HID + lane;
  const float* ST  = ws + OFF_ST;
  const float* MSG = ws + OFF_MSG;

  const float v = x[idx] + ST[idx] + MSG[idx];
  float mu = v;
#pragma unroll
  for (int o = 1; o < 64; o <<= 1) mu += __shfl_xor(mu, o, 64);
  mu *= (1.0f / 64.0f);
  const float dv = v - mu;
  float var = dv * dv;
#pragma unroll
  for (int o = 1; o < 64; o <<= 1) var += __shfl_xor(var, o, 64);
  var *= (1.0f / 64.0f);
  out[idx] = dv * rsqrtf(var + LN_EPS) * gamma[lane] + beta[lane];
}

// ---------------------------------------------------------------------------
extern "C" void kernel_launch(void* const* d_in, const int* in_sizes, int n_in,
                              void* d_out, int out_size, void* d_ws, size_t ws_size,
                              hipStream_t stream)
{
  const float* x   = (const float*)d_in[0];
  const int*   adj = (const int*)d_in[1];
  const float* ef  = (const float*)d_in[2];
  const float* W1w = (const float*)d_in[3];
  const float* W1b = (const float*)d_in[4];
  const float* W2w = (const float*)d_in[5];
  const float* W2b = (const float*)d_in[6];
  const float* W3w = (const float*)d_in[7];
  const float* W3b = (const float*)d_in[8];
  const float* W4w = (const float*)d_in[9];
  const float* W4b = (const float*)d_in[10];
  const float* W5w = (const float*)d_in[11];
  const float* W5b = (const float*)d_in[12];
  const float* lng = (const float*)d_in[13];
  const float* lnb = (const float*)d_in[14];
  float* ws  = (float*)d_ws;
  float* out = (float*)d_out;

  proj_kernel<<<128, 256, 0, stream>>>(x, W1w, W1b, W2w, W2b, W3w, W3b, W4w, W4b, ws);
  attn_kernel<<<dim3(32, HEADS, B), 256, 0, stream>>>(adj, ef, W5w, W5b, ws);
  ln_kernel<<<ROWS / 4, 256, 0, stream>>>(x, ws, lng, lnb, out);
}